// Round 9
// baseline (161.069 us; speedup 1.0000x reference)
//
#include <hip/hip_runtime.h>
#include <math.h>

#define T_LEN 2048
#define NB 2
#define E_DIM 1024
#define F_DIM 1536
#define HQn 16
#define HKn 4
#define Dh 64
#define WIN 1024
#define GATE_CH 12
#define PS 72   // LDS row stride (elems) for K attn tile: 144B, 16B-aligned
#define PSV 68  // LDS row stride for V attn tile: 136B -> bank base 2*row, conflict-free b64
#define CS 73   // LDS row stride for gemm1 epilogue C-tile (odd: bank spread)

typedef unsigned short u16;
typedef unsigned int u32;
typedef __attribute__((ext_vector_type(8))) short bf16x8;
typedef __attribute__((ext_vector_type(4))) short bf16x4;
typedef __attribute__((ext_vector_type(4))) float f32x4;

// K=16 bf16 MFMA: probe builtin names; asm fallback (instr exists on gfx950).
#if __has_builtin(__builtin_amdgcn_mfma_f32_16x16x16bf16_1k)
#define MFMA16(A, B, C) __builtin_amdgcn_mfma_f32_16x16x16bf16_1k(A, B, C, 0, 0, 0)
#elif __has_builtin(__builtin_amdgcn_mfma_f32_16x16x16_bf16)
#define MFMA16(A, B, C) __builtin_amdgcn_mfma_f32_16x16x16_bf16(A, B, C, 0, 0, 0)
#else
static __device__ __forceinline__ f32x4 mfma16_asm(bf16x4 a, bf16x4 b, f32x4 c) {
  f32x4 d;
  asm volatile("s_nop 1\n\tv_mfma_f32_16x16x16_bf16 %0, %1, %2, %3\n\ts_nop 7\n\ts_nop 7"
               : "=v"(d) : "v"(a), "v"(b), "v"(c));
  return d;
}
#define MFMA16(A, B, C) mfma16_asm(A, B, C)
#endif

__device__ __forceinline__ u16 f2bf(float f) {
  union { float f; unsigned int u; } v; v.f = f;
  unsigned int u = v.u + 0x7FFF + ((v.u >> 16) & 1);
  return (u16)(u >> 16);
}
__device__ __forceinline__ float bf2f(u16 h) {
  union { unsigned int u; float f; } v; v.u = ((unsigned int)h) << 16;
  return v.f;
}
// pack two f32 -> two bf16 (round-half-up) in ONE v_perm + 2 adds
__device__ __forceinline__ u32 pack_bf2(float hi, float lo) {
  union { float f; u32 u; } a, b; a.f = hi; b.f = lo;
  return __builtin_amdgcn_perm(a.u + 0x8000u, b.u + 0x8000u, 0x07060302u);
}
__device__ __forceinline__ void async_copy16(const void* g, void* l) {
  __builtin_amdgcn_global_load_lds(
      (const __attribute__((address_space(1))) unsigned int*)g,
      (__attribute__((address_space(3))) unsigned int*)l, 16, 0, 0);
}

// ---------------------------------------------------------------------------
// fp32 -> bf16 (RNE) for x / wqkv / wo in ONE launch.
// blocks [0,4096) x | [4096,5632) wqkv | [5632,6656) wo
// ---------------------------------------------------------------------------
__global__ __launch_bounds__(256) void cvt_all(
    const float4* __restrict__ x, const float4* __restrict__ wqkv,
    const float4* __restrict__ wo, uint2* __restrict__ xb,
    uint2* __restrict__ wqb, uint2* __restrict__ wob)
{
  int blk = blockIdx.x;
  const float4* in; uint2* out; int i;
  if (blk < 4096)       { in = x;    out = xb;  i = blk * 256 + threadIdx.x; }
  else if (blk < 5632)  { in = wqkv; out = wqb; i = (blk - 4096) * 256 + threadIdx.x; }
  else                  { in = wo;   out = wob; i = (blk - 5632) * 256 + threadIdx.x; }
  float4 v = in[i];
  uint2 o;
  o.x = (unsigned)f2bf(v.x) | ((unsigned)f2bf(v.y) << 16);
  o.y = (unsigned)f2bf(v.z) | ((unsigned)f2bf(v.w) << 16);
  out[i] = o;
}

// ---------------------------------------------------------------------------
// QKV GEMM + FUSED epilogue. R19: MAX WAVES. The one confirmed lever this
// session is resident-wave count (R15 12w/CU=52us -> R16 20w/CU=40us; all
// pipeline/LDS/XCD theories nulled -> latency-bound, wave-starved).
// Same 64x64 tile, same 32 KB LDS, same counted-vmcnt skeleton, but 512
// threads (8 waves): 4 blk/CU x 8 waves = 32 waves/CU (HW max, was 20).
// Per-wave tile 16x32 (1x2 frags, acc 8 VGPR -> total VGPR ~50 < 64 step).
// Stage = 1 A-load + 1 B-load per thread -> vmcnt(2) steady state.
// grid (64,24). blockIdx.y: head 0-15 q | 16-19 k | 20-23 v.
// ---------------------------------------------------------------------------
__global__ __launch_bounds__(512) void gemm_qkv(
    const u16* __restrict__ A, const u16* __restrict__ B,
    const float* __restrict__ x, const float* __restrict__ ve,
    const float* __restrict__ rcos, const float* __restrict__ rsin,
    const float* __restrict__ wg,
    u16* __restrict__ qa, u16* __restrict__ ka, u16* __restrict__ vt)
{
  constexpr int K = E_DIM;
  constexpr int NT = K / 64;            // 16 K-tiles
  __shared__ u16 smem[16384];           // 32 KB exactly: As[2][4096] Bs[2][4096]
  u16* As = smem;                       // bufs at 0, 4096
  u16* Bs = smem + 8192;                // bufs at 8192, 12288
  u16* Ct = smem;                       // [64][CS] = 4672 u16 (epilogue reuse)
  float* gateL = (float*)(smem + 4672); // 64 floats (4-aligned)
  const int tid = threadIdx.x;
  const int wave = tid >> 6, lane = tid & 63;
  const int quad = lane >> 4, lanelow = lane & 15;
  const int row0 = blockIdx.x * 64;     // token base
  const int h    = blockIdx.y;          // head 0..23
  const int col0 = h * 64;
  const int wm = (wave >> 1) * 16;      // 4 row-groups of 16
  const int wn = (wave & 1) * 32;       // 2 col-groups of 32

  f32x4 acc[2];
  acc[0] = (f32x4){0.f, 0.f, 0.f, 0.f};
  acc[1] = (f32x4){0.f, 0.f, 0.f, 0.f};

  // stage one BK=64 tile (A:64x64, B:64x64) = 2 loads/thread (512 thr).
  // global source granule XOR-swizzled so linear LDS holds swizzled layout.
  const int sr = tid >> 3, sg = (tid & 7) ^ ((tid >> 3) & 7);
  auto stage = [&](int buf, int k0) {
    async_copy16(A + (size_t)(row0 + sr) * K + k0 + sg * 8,
                 &As[buf * 4096 + tid * 8]);
    async_copy16(B + (size_t)(col0 + sr) * K + k0 + sg * 8,
                 &Bs[buf * 4096 + tid * 8]);
  };

  stage(0, 0);
  stage(1, 64);
  int cur = 0;
  for (int t = 0; t < NT; ++t) {
    if (t < NT - 1) asm volatile("s_waitcnt vmcnt(2)" ::: "memory");
    else            asm volatile("s_waitcnt vmcnt(0)" ::: "memory");
    __builtin_amdgcn_s_barrier();
    __builtin_amdgcn_sched_barrier(0);
#pragma unroll
    for (int kk = 0; kk < 2; ++kk) {
      bf16x8 a, b[2];
      {
        int r = wm + lanelow;
        a = *(const bf16x8*)&As[cur * 4096 + r * 64 + (((kk * 4 + quad) ^ (r & 7)) * 8)];
      }
#pragma unroll
      for (int j = 0; j < 2; ++j) {
        int r = wn + j * 16 + lanelow;
        b[j] = *(const bf16x8*)&Bs[cur * 4096 + r * 64 + (((kk * 4 + quad) ^ (r & 7)) * 8)];
      }
      __builtin_amdgcn_s_setprio(1);
#pragma unroll
      for (int j = 0; j < 2; ++j)
        acc[j] = __builtin_amdgcn_mfma_f32_16x16x32_bf16(a, b[j], acc[j], 0, 0, 0);
      __builtin_amdgcn_s_setprio(0);
    }
    __builtin_amdgcn_sched_barrier(0);
    __builtin_amdgcn_s_barrier();       // all reads of buf `cur` done
    if (t + 2 < NT) stage(cur, (t + 2) * 64);
    cur ^= 1;
  }

  // ---- fused epilogue ---- (final s_barrier above: all frag reads done)
#pragma unroll
  for (int j = 0; j < 2; ++j)
#pragma unroll
    for (int reg = 0; reg < 4; ++reg) {
      int row = wm + quad * 4 + reg;
      int col = wn + j * 16 + lanelow;
      Ct[row * CS + col] = f2bf(acc[j][reg]);
    }
  __syncthreads();

  if (h < HQn + HKn) {                  // q or k head: RoPE + RMS
    const bool isq = (h < HQn);
    const int half = lane & 31;
    for (int t = wave * 8; t < wave * 8 + 8; ++t) {
      int tok = row0 + t;
      int tt = tok & (T_LEN - 1);
      float c = rcos[tt * 32 + half], s = rsin[tt * 32 + half];
      float x1 = bf2f(Ct[t * CS + half]);
      float x2 = bf2f(Ct[t * CS + half + 32]);
      float y = (lane < 32) ? (x1 * c - x2 * s) : (x1 * s + x2 * c);
      float ss = y * y;
#pragma unroll
      for (int o = 32; o; o >>= 1) ss += __shfl_xor(ss, o, 64);
      float v = y * rsqrtf(ss * (1.f / Dh) + 1e-8f);
      if (isq)
        qa[((size_t)tok * HQn + h) * Dh + lane] = f2bf(v * 0.1803368801f); // 0.125*log2(e)
      else
        ka[((size_t)tok * HKn + (h - HQn)) * Dh + lane] = f2bf(v);
    }
  } else {                              // v head: gate + ve, transposed store
    const int hk = h - (HQn + HKn);
    if (tid < 64) {
      int tok = row0 + tid;
      float g = 0.f;
#pragma unroll
      for (int c = 0; c < GATE_CH; ++c)
        g += x[(size_t)tok * E_DIM + c] * wg[hk * GATE_CH + c];
      gateL[tid] = 3.f / (1.f + __expf(-g));
    }
    __syncthreads();
    for (int t = wave * 8; t < wave * 8 + 8; ++t) {
      int tok = row0 + t;
      float val = bf2f(Ct[t * CS + lane]) +
                  gateL[t] * ve[(size_t)tok * (HKn * Dh) + hk * Dh + lane];
      Ct[t * CS + lane] = f2bf(val);
    }
    __syncthreads();
    // transposed readout: 512 threads -> (d, 8-token segment)
    int d = tid >> 3, tseg = (tid & 7) * 8;
    int tokbase = row0 + tseg;
    int b = tokbase >> 11;              // uniform per block (64 | 2048)
    int tloc = tokbase & (T_LEN - 1);
    u16 tmp[8];
#pragma unroll
    for (int e = 0; e < 8; ++e) tmp[e] = Ct[(tseg + e) * CS + d];
    u16* dst = vt + ((size_t)(b * HKn + hk) * Dh + d) * T_LEN + tloc;
    *(uint4*)dst = *(uint4*)&tmp[0];
  }
}

// ---------------------------------------------------------------------------
// Output projection GEMM. R19: same max-wave change — 512 threads, 16x32
// per-wave tile, vmcnt(2), 32 KB LDS -> 4 blk x 8 waves = 32 waves/CU.
// grid (64,16) = 1024 blocks.
// ---------------------------------------------------------------------------
__global__ __launch_bounds__(512) void gemm_wo(
    const u16* __restrict__ A, const u16* __restrict__ B,
    float* __restrict__ C, int N, int K)
{
  const int NT = K / 64;
  __shared__ u16 smem[16384];           // As[2][4096] + Bs[2][4096]
  u16* As = smem;
  u16* Bs = smem + 8192;
  const int tid = threadIdx.x;
  const int wave = tid >> 6, lane = tid & 63;
  const int quad = lane >> 4, lanelow = lane & 15;
  const int row0 = blockIdx.x * 64;
  const int col0 = blockIdx.y * 64;
  const int wm = (wave >> 1) * 16;
  const int wn = (wave & 1) * 32;

  f32x4 acc[2];
  acc[0] = (f32x4){0.f, 0.f, 0.f, 0.f};
  acc[1] = (f32x4){0.f, 0.f, 0.f, 0.f};

  const int sr = tid >> 3, sg = (tid & 7) ^ ((tid >> 3) & 7);
  auto stage = [&](int buf, int k0) {
    async_copy16(A + (size_t)(row0 + sr) * K + k0 + sg * 8,
                 &As[buf * 4096 + tid * 8]);
    async_copy16(B + (size_t)(col0 + sr) * K + k0 + sg * 8,
                 &Bs[buf * 4096 + tid * 8]);
  };

  stage(0, 0);
  stage(1, 64);
  int cur = 0;
  for (int t = 0; t < NT; ++t) {
    if (t < NT - 1) asm volatile("s_waitcnt vmcnt(2)" ::: "memory");
    else            asm volatile("s_waitcnt vmcnt(0)" ::: "memory");
    __builtin_amdgcn_s_barrier();
    __builtin_amdgcn_sched_barrier(0);
#pragma unroll
    for (int kk = 0; kk < 2; ++kk) {
      bf16x8 a, b[2];
      {
        int r = wm + lanelow;
        a = *(const bf16x8*)&As[cur * 4096 + r * 64 + (((kk * 4 + quad) ^ (r & 7)) * 8)];
      }
#pragma unroll
      for (int j = 0; j < 2; ++j) {
        int r = wn + j * 16 + lanelow;
        b[j] = *(const bf16x8*)&Bs[cur * 4096 + r * 64 + (((kk * 4 + quad) ^ (r & 7)) * 8)];
      }
      __builtin_amdgcn_s_setprio(1);
#pragma unroll
      for (int j = 0; j < 2; ++j)
        acc[j] = __builtin_amdgcn_mfma_f32_16x16x32_bf16(a, b[j], acc[j], 0, 0, 0);
      __builtin_amdgcn_s_setprio(0);
    }
    __builtin_amdgcn_sched_barrier(0);
    __builtin_amdgcn_s_barrier();
    if (t + 2 < NT) stage(cur, (t + 2) * 64);
    cur ^= 1;
  }

#pragma unroll
  for (int j = 0; j < 2; ++j) {
    int r = row0 + wm + quad * 4;
    int c = col0 + wn + j * 16 + lanelow;
#pragma unroll
    for (int reg = 0; reg < 4; ++reg)
      C[(size_t)(r + reg) * N + c] = acc[j][reg];
  }
}

// ---------------------------------------------------------------------------
// MFMA flash attention. R18's T14 async-STAGE split kept (measured win):
//   issue loads(t+1) -> lgkmcnt(0) + raw s_barrier [loads stay in flight]
//   -> QK/softmax/PV (hides latency) -> vmcnt(0) -> write nbuf.
// S^T formulation, fixed-shift softmax, qt load-balance permutation,
// Vt stride 68 conflict-free b64.
// ---------------------------------------------------------------------------
__global__ __launch_bounds__(256) void attn_mfma(
    const u16* __restrict__ qa, const u16* __restrict__ ka,
    const u16* __restrict__ vt_g, u16* __restrict__ att)
{
  __shared__ u16 Ks[2][64 * PS];    // [buf][j][d]
  __shared__ u16 Vt[2][64 * PSV];   // [buf][d][j]
  const int bx = blockIdx.x, h = blockIdx.y, b = blockIdx.z;
  // --- load-balance permutation: bijective in bx for each (h,b) ---
  const int j5 = bx & 7;
  const int t5 = (bx >> 3) & 3;
  const int tu = (t5 + (h >> 3) + 2 * b) & 3;
  const int qt = (tu == 0) ? j5
               : (tu == 1) ? (15 - j5)
                           : (16 + 2 * j5 + (tu & 1));
  const int hk = h >> 2;
  const int qb = qt * 64;
  const int tid = threadIdx.x;
  const int wave = tid >> 6, lane = tid & 63;
  const int quad = lane >> 4, lanelow = lane & 15;

  bf16x8 aQ[2];
#pragma unroll
  for (int kk = 0; kk < 2; ++kk)
    aQ[kk] = *(const bf16x8*)(qa +
        ((size_t)(b * T_LEN + qb + wave * 16 + lanelow) * HQn + h) * Dh +
        kk * 32 + quad * 8);

  f32x4 O[4];
  float l = 0.f;
#pragma unroll
  for (int dt = 0; dt < 4; ++dt) O[dt] = (f32x4){0.f, 0.f, 0.f, 0.f};

  const int kt0 = (qt >= 16) ? qt - 16 : 0;
  const int kt1 = qt;

  const int sr0 = tid >> 3,         sc0 = (tid & 7) * 8;
  const int sr1 = (tid + 256) >> 3, sc1 = ((tid + 256) & 7) * 8;
  const u16* kg = ka + (size_t)(b * T_LEN) * (HKn * Dh) + hk * Dh;
  const u16* vg = vt_g + (size_t)(b * HKn + hk) * Dh * T_LEN;

  {
    const int kb = kt0 * 64;
    uint4 k0 = *(const uint4*)(kg + (size_t)(kb + sr0) * (HKn * Dh) + sc0);
    uint4 k1 = *(const uint4*)(kg + (size_t)(kb + sr1) * (HKn * Dh) + sc1);
    uint4 v0 = *(const uint4*)(vg + (size_t)sr0 * T_LEN + kb + sc0);
    uint4 v1 = *(const uint4*)(vg + (size_t)sr1 * T_LEN + kb + sc1);
    *(uint4*)&Ks[0][sr0 * PS + sc0] = k0;
    *(uint4*)&Ks[0][sr1 * PS + sc1] = k1;
    *(uint2*)&Vt[0][sr0 * PSV + sc0]     = make_uint2(v0.x, v0.y);
    *(uint2*)&Vt[0][sr0 * PSV + sc0 + 4] = make_uint2(v0.z, v0.w);
    *(uint2*)&Vt[0][sr1 * PSV + sc1]     = make_uint2(v1.x, v1.y);
    *(uint2*)&Vt[0][sr1 * PSV + sc1 + 4] = make_uint2(v1.z, v1.w);
  }

  for (int kt = kt0; kt <= kt1; ++kt) {
    const int buf = (kt - kt0) & 1;
    const int kb = kt * 64;
    uint4 k0, k1, v0, v1;
    const bool more = (kt < kt1);
    if (more) {
      const int nb = kb + 64;
      k0 = *(const uint4*)(kg + (size_t)(nb + sr0) * (HKn * Dh) + sc0);
      k1 = *(const uint4*)(kg + (size_t)(nb + sr1) * (HKn * Dh) + sc1);
      v0 = *(const uint4*)(vg + (size_t)sr0 * T_LEN + nb + sc0);
      v1 = *(const uint4*)(vg + (size_t)sr1 * T_LEN + nb + sc1);
    }
    // T14: LDS-only fence + raw barrier; global loads stay in flight.
    __builtin_amdgcn_sched_barrier(0);
    asm volatile("s_waitcnt lgkmcnt(0)" ::: "memory");
    __builtin_amdgcn_s_barrier();
    __builtin_amdgcn_sched_barrier(0);

    f32x4 St[4];
#pragma unroll
    for (int jt = 0; jt < 4; ++jt) {
      bf16x8 aK0 = *(const bf16x8*)&Ks[buf][(jt * 16 + lanelow) * PS + quad * 8];
      bf16x8 aK1 = *(const bf16x8*)&Ks[buf][(jt * 16 + lanelow) * PS + 32 + quad * 8];
      f32x4 acc = (f32x4){-12.f, -12.f, -12.f, -12.f};
      acc = __builtin_amdgcn_mfma_f32_16x16x32_bf16(aK0, aQ[0], acc, 0, 0, 0);
      acc = __builtin_amdgcn_mfma_f32_16x16x32_bf16(aK1, aQ[1], acc, 0, 0, 0);
      St[jt] = acc;
    }
    if (kt == kt1) {
#pragma unroll
      for (int jt = 0; jt < 4; ++jt)
#pragma unroll
        for (int rr = 0; rr < 4; ++rr) {
          int ig = qb + wave * 16 + lanelow;
          int jg = kb + jt * 16 + quad * 4 + rr;
          if (jg > ig) St[jt][rr] = -1e30f;
        }
    } else if (kt == kt0 && qt >= 16) {
#pragma unroll
      for (int jt = 0; jt < 4; ++jt)
#pragma unroll
        for (int rr = 0; rr < 4; ++rr) {
          int ig = qb + wave * 16 + lanelow;
          int jg = kb + jt * 16 + quad * 4 + rr;
          if (jg < ig - WIN) St[jt][rr] = -1e30f;
        }
    }
    bf16x4 Pt[4];
#pragma unroll
    for (int jt = 0; jt < 4; ++jt) {
      float p0 = __builtin_amdgcn_exp2f(St[jt][0]);
      float p1 = __builtin_amdgcn_exp2f(St[jt][1]);
      float p2 = __builtin_amdgcn_exp2f(St[jt][2]);
      float p3 = __builtin_amdgcn_exp2f(St[jt][3]);
      l += (p0 + p1) + (p2 + p3);
      union { uint2 u; bf16x4 v; } pu;
      pu.u.x = pack_bf2(p1, p0);
      pu.u.y = pack_bf2(p3, p2);
      Pt[jt] = pu.v;
    }
#pragma unroll
    for (int dt = 0; dt < 4; ++dt)
#pragma unroll
      for (int jt = 0; jt < 4; ++jt) {
        bf16x4 aV = *(const bf16x4*)&Vt[buf][(dt * 16 + lanelow) * PSV + jt * 16 + quad * 4];
        O[dt] = MFMA16(aV, Pt[jt], O[dt]);
      }
    if (more) {
      // T14: drain THIS wave's 4 loads only now, after compute hid latency.
      __builtin_amdgcn_sched_barrier(0);
      asm volatile("s_waitcnt vmcnt(0)" ::: "memory");
      __builtin_amdgcn_sched_barrier(0);
      const int nbuf = buf ^ 1;
      *(uint4*)&Ks[nbuf][sr0 * PS + sc0] = k0;
      *(uint4*)&Ks[nbuf][sr1 * PS + sc1] = k1;
      *(uint2*)&Vt[nbuf][sr0 * PSV + sc0]     = make_uint2(v0.x, v0.y);
      *(uint2*)&Vt[nbuf][sr0 * PSV + sc0 + 4] = make_uint2(v0.z, v0.w);
      *(uint2*)&Vt[nbuf][sr1 * PSV + sc1]     = make_uint2(v1.x, v1.y);
      *(uint2*)&Vt[nbuf][sr1 * PSV + sc1 + 4] = make_uint2(v1.z, v1.w);
    }
  }

  {
    float s = l;
    s += __shfl_xor(s, 16, 64);
    s += __shfl_xor(s, 32, 64);
    float inv = 1.f / s;
    int qg = qb + wave * 16 + lanelow;
    u16* obase = att + (size_t)(b * T_LEN + qg) * E_DIM + h * Dh;
#pragma unroll
    for (int dt = 0; dt < 4; ++dt) {
      bf16x4 ov;
      ov[0] = (short)f2bf(O[dt][0] * inv);
      ov[1] = (short)f2bf(O[dt][1] * inv);
      ov[2] = (short)f2bf(O[dt][2] * inv);
      ov[3] = (short)f2bf(O[dt][3] * inv);
      *(bf16x4*)(obase + dt * 16 + quad * 4) = ov;
    }
  }
}

// ---------------------------------------------------------------------------
extern "C" void kernel_launch(void* const* d_in, const int* in_sizes, int n_in,
                              void* d_out, int out_size, void* d_ws, size_t ws_size,
                              hipStream_t stream)
{
  const float* x    = (const float*)d_in[0];
  const float* ve   = (const float*)d_in[1];
  const float* rc   = (const float*)d_in[2];
  const float* rs   = (const float*)d_in[3];
  const float* wqkv = (const float*)d_in[4];
  const float* wg   = (const float*)d_in[5];
  const float* wo   = (const float*)d_in[6];
  float* out = (float*)d_out;

  char* ws = (char*)d_ws;
  // ws layout — ALL ranges disjoint:
  //   [0,        8388608)  x_bf      4096x1024 bf16
  //   [8388608, 11534336)  wqkv_bf   1536x1024 bf16
  //   [11534336,13631488)  wo_bf     1024x1024 bf16
  //   [13631488,22020096)  q_att     4096x16x64 bf16
  //   [22020096,24117248)  k_att     4096x4x64 bf16
  //   [24117248,26214400)  v_t       (2*4*64)x2048 bf16
  //   [26214400,34603008)  att       4096x1024 bf16
  u16* x_bf    = (u16*)(ws);
  u16* wqkv_bf = (u16*)(ws + 8388608);
  u16* wo_bf   = (u16*)(ws + 11534336);
  u16* q_att   = (u16*)(ws + 13631488);
  u16* k_att   = (u16*)(ws + 22020096);
  u16* v_t     = (u16*)(ws + 24117248);
  u16* att     = (u16*)(ws + 26214400);

  cvt_all<<<6656, 256, 0, stream>>>((const float4*)x, (const float4*)wqkv,
                                    (const float4*)wo, (uint2*)x_bf,
                                    (uint2*)wqkv_bf, (uint2*)wo_bf);
  gemm_qkv<<<dim3(64, 24), 512, 0, stream>>>(x_bf, wqkv_bf, x, ve, rc, rs, wg,
                                             q_att, k_att, v_t);
  attn_mfma<<<dim3(T_LEN / 64, HQn, NB), 256, 0, stream>>>(q_att, k_att, v_t, att);
  gemm_wo<<<dim3(64, 16), 512, 0, stream>>>(att, wo_bf, out, E_DIM, E_DIM);
}

// Round 10
// 155.736 us; speedup vs baseline: 1.0342x; 1.0342x over previous
//
#include <hip/hip_runtime.h>
#include <math.h>

#define T_LEN 2048
#define NB 2
#define E_DIM 1024
#define F_DIM 1536
#define HQn 16
#define HKn 4
#define Dh 64
#define WIN 1024
#define GATE_CH 12
#define PS 72   // LDS row stride (elems) for K attn tile: 144B, 16B-aligned
#define PSV 68  // LDS row stride for V attn tile: 136B -> bank base 2*row, conflict-free b64
#define CS 73   // LDS row stride for gemm1 epilogue C-tile (odd: bank spread)

typedef unsigned short u16;
typedef unsigned int u32;
typedef __attribute__((ext_vector_type(8))) short bf16x8;
typedef __attribute__((ext_vector_type(4))) short bf16x4;
typedef __attribute__((ext_vector_type(4))) float f32x4;

// K=16 bf16 MFMA: probe builtin names; asm fallback (instr exists on gfx950).
#if __has_builtin(__builtin_amdgcn_mfma_f32_16x16x16bf16_1k)
#define MFMA16(A, B, C) __builtin_amdgcn_mfma_f32_16x16x16bf16_1k(A, B, C, 0, 0, 0)
#elif __has_builtin(__builtin_amdgcn_mfma_f32_16x16x16_bf16)
#define MFMA16(A, B, C) __builtin_amdgcn_mfma_f32_16x16x16_bf16(A, B, C, 0, 0, 0)
#else
static __device__ __forceinline__ f32x4 mfma16_asm(bf16x4 a, bf16x4 b, f32x4 c) {
  f32x4 d;
  asm volatile("s_nop 1\n\tv_mfma_f32_16x16x16_bf16 %0, %1, %2, %3\n\ts_nop 7\n\ts_nop 7"
               : "=v"(d) : "v"(a), "v"(b), "v"(c));
  return d;
}
#define MFMA16(A, B, C) mfma16_asm(A, B, C)
#endif

__device__ __forceinline__ u16 f2bf(float f) {
  union { float f; unsigned int u; } v; v.f = f;
  unsigned int u = v.u + 0x7FFF + ((v.u >> 16) & 1);
  return (u16)(u >> 16);
}
__device__ __forceinline__ float bf2f(u16 h) {
  union { unsigned int u; float f; } v; v.u = ((unsigned int)h) << 16;
  return v.f;
}
// pack two f32 -> two bf16 (round-half-up) in ONE v_perm + 2 adds
__device__ __forceinline__ u32 pack_bf2(float hi, float lo) {
  union { float f; u32 u; } a, b; a.f = hi; b.f = lo;
  return __builtin_amdgcn_perm(a.u + 0x8000u, b.u + 0x8000u, 0x07060302u);
}
__device__ __forceinline__ void async_copy16(const void* g, void* l) {
  __builtin_amdgcn_global_load_lds(
      (const __attribute__((address_space(1))) unsigned int*)g,
      (__attribute__((address_space(3))) unsigned int*)l, 16, 0, 0);
}

// ---------------------------------------------------------------------------
// fp32 -> bf16 (RNE) for x / wqkv / wo in ONE launch.
// blocks [0,4096) x | [4096,5632) wqkv | [5632,6656) wo
// ---------------------------------------------------------------------------
__global__ __launch_bounds__(256) void cvt_all(
    const float4* __restrict__ x, const float4* __restrict__ wqkv,
    const float4* __restrict__ wo, uint2* __restrict__ xb,
    uint2* __restrict__ wqb, uint2* __restrict__ wob)
{
  int blk = blockIdx.x;
  const float4* in; uint2* out; int i;
  if (blk < 4096)       { in = x;    out = xb;  i = blk * 256 + threadIdx.x; }
  else if (blk < 5632)  { in = wqkv; out = wqb; i = (blk - 4096) * 256 + threadIdx.x; }
  else                  { in = wo;   out = wob; i = (blk - 5632) * 256 + threadIdx.x; }
  float4 v = in[i];
  uint2 o;
  o.x = (unsigned)f2bf(v.x) | ((unsigned)f2bf(v.y) << 16);
  o.y = (unsigned)f2bf(v.z) | ((unsigned)f2bf(v.w) << 16);
  out[i] = o;
}

// ---------------------------------------------------------------------------
// QKV GEMM + FUSED epilogue. R20 = R18 exact (best measured: 158.4 us;
// R19's 512-thread max-wave variant regressed and is reverted).
// BM=BN=64, BK=64 double-buffer, counted vmcnt(4), XOR-granule swizzle,
// 32 KB LDS -> 5 blk/CU (20 waves). grid (64,24).
// blockIdx.y: head 0-15 q | 16-19 k | 20-23 v.
// ---------------------------------------------------------------------------
__global__ __launch_bounds__(256) void gemm_qkv(
    const u16* __restrict__ A, const u16* __restrict__ B,
    const float* __restrict__ x, const float* __restrict__ ve,
    const float* __restrict__ rcos, const float* __restrict__ rsin,
    const float* __restrict__ wg,
    u16* __restrict__ qa, u16* __restrict__ ka, u16* __restrict__ vt)
{
  constexpr int K = E_DIM;
  constexpr int NT = K / 64;            // 16 K-tiles
  __shared__ u16 smem[16384];           // 32 KB exactly: As[2][4096] Bs[2][4096]
  u16* As = smem;                       // bufs at 0, 4096
  u16* Bs = smem + 8192;                // bufs at 8192, 12288
  u16* Ct = smem;                       // [64][CS] = 4672 u16 (epilogue reuse)
  float* gateL = (float*)(smem + 4672); // 64 floats (4-aligned)
  const int tid = threadIdx.x;
  const int wave = tid >> 6, lane = tid & 63;
  const int quad = lane >> 4, lanelow = lane & 15;
  const int row0 = blockIdx.x * 64;     // token base
  const int h    = blockIdx.y;          // head 0..23
  const int col0 = h * 64;
  const int wm = (wave >> 1) * 32, wn = (wave & 1) * 32;

  f32x4 acc[2][2];
#pragma unroll
  for (int i = 0; i < 2; ++i)
#pragma unroll
    for (int j = 0; j < 2; ++j) acc[i][j] = (f32x4){0.f, 0.f, 0.f, 0.f};

  // stage one BK=64 tile (A:64x64, B:64x64) = 4 loads/thread.
  // global source granule XOR-swizzled so linear LDS holds swizzled layout.
  auto stage = [&](int buf, int k0) {
#pragma unroll
    for (int s = 0; s < 2; ++s) {
      int slot = s * 256 + tid;
      int r = slot >> 3, g = (slot & 7) ^ (r & 7);
      async_copy16(A + (size_t)(row0 + r) * K + k0 + g * 8,
                   &As[buf * 4096 + slot * 8]);
    }
#pragma unroll
    for (int s = 0; s < 2; ++s) {
      int slot = s * 256 + tid;
      int r = slot >> 3, g = (slot & 7) ^ (r & 7);
      async_copy16(B + (size_t)(col0 + r) * K + k0 + g * 8,
                   &Bs[buf * 4096 + slot * 8]);
    }
  };

  stage(0, 0);
  stage(1, 64);
  int cur = 0;
  for (int t = 0; t < NT; ++t) {
    if (t < NT - 1) asm volatile("s_waitcnt vmcnt(4)" ::: "memory");
    else            asm volatile("s_waitcnt vmcnt(0)" ::: "memory");
    __builtin_amdgcn_s_barrier();
    __builtin_amdgcn_sched_barrier(0);
#pragma unroll
    for (int kk = 0; kk < 2; ++kk) {
      bf16x8 a[2], b[2];
#pragma unroll
      for (int i = 0; i < 2; ++i) {
        int r = wm + i * 16 + lanelow;
        a[i] = *(const bf16x8*)&As[cur * 4096 + r * 64 + (((kk * 4 + quad) ^ (r & 7)) * 8)];
      }
#pragma unroll
      for (int j = 0; j < 2; ++j) {
        int r = wn + j * 16 + lanelow;
        b[j] = *(const bf16x8*)&Bs[cur * 4096 + r * 64 + (((kk * 4 + quad) ^ (r & 7)) * 8)];
      }
      __builtin_amdgcn_s_setprio(1);
#pragma unroll
      for (int i = 0; i < 2; ++i)
#pragma unroll
        for (int j = 0; j < 2; ++j)
          acc[i][j] = __builtin_amdgcn_mfma_f32_16x16x32_bf16(a[i], b[j], acc[i][j], 0, 0, 0);
      __builtin_amdgcn_s_setprio(0);
    }
    __builtin_amdgcn_sched_barrier(0);
    __builtin_amdgcn_s_barrier();       // all reads of buf `cur` done
    if (t + 2 < NT) stage(cur, (t + 2) * 64);
    cur ^= 1;
  }

  // ---- fused epilogue ---- (final s_barrier above: all frag reads done)
#pragma unroll
  for (int i = 0; i < 2; ++i)
#pragma unroll
    for (int j = 0; j < 2; ++j)
#pragma unroll
      for (int reg = 0; reg < 4; ++reg) {
        int row = wm + i * 16 + quad * 4 + reg;
        int col = wn + j * 16 + lanelow;
        Ct[row * CS + col] = f2bf(acc[i][j][reg]);
      }
  __syncthreads();

  if (h < HQn + HKn) {                  // q or k head: RoPE + RMS
    const bool isq = (h < HQn);
    const int half = lane & 31;
    for (int t = wave * 16; t < wave * 16 + 16; ++t) {
      int tok = row0 + t;
      int tt = tok & (T_LEN - 1);
      float c = rcos[tt * 32 + half], s = rsin[tt * 32 + half];
      float x1 = bf2f(Ct[t * CS + half]);
      float x2 = bf2f(Ct[t * CS + half + 32]);
      float y = (lane < 32) ? (x1 * c - x2 * s) : (x1 * s + x2 * c);
      float ss = y * y;
#pragma unroll
      for (int o = 32; o; o >>= 1) ss += __shfl_xor(ss, o, 64);
      float v = y * rsqrtf(ss * (1.f / Dh) + 1e-8f);
      if (isq)
        qa[((size_t)tok * HQn + h) * Dh + lane] = f2bf(v * 0.1803368801f); // 0.125*log2(e)
      else
        ka[((size_t)tok * HKn + (h - HQn)) * Dh + lane] = f2bf(v);
    }
  } else {                              // v head: gate + ve, transposed store
    const int hk = h - (HQn + HKn);
    if (tid < 64) {
      int tok = row0 + tid;
      float g = 0.f;
#pragma unroll
      for (int c = 0; c < GATE_CH; ++c)
        g += x[(size_t)tok * E_DIM + c] * wg[hk * GATE_CH + c];
      gateL[tid] = 3.f / (1.f + __expf(-g));
    }
    __syncthreads();
    for (int t = wave * 16; t < wave * 16 + 16; ++t) {
      int tok = row0 + t;
      float val = bf2f(Ct[t * CS + lane]) +
                  gateL[t] * ve[(size_t)tok * (HKn * Dh) + hk * Dh + lane];
      Ct[t * CS + lane] = f2bf(val);
    }
    __syncthreads();
    // transposed readout: thread -> (d, 16-token segment)
    int d = tid >> 2, tseg = (tid & 3) * 16;
    int tokbase = row0 + tseg;
    int b = tokbase >> 11;              // uniform per block (64 | 2048)
    int tloc = tokbase & (T_LEN - 1);
    u16 tmp[16];
#pragma unroll
    for (int e = 0; e < 16; ++e) tmp[e] = Ct[(tseg + e) * CS + d];
    u16* dst = vt + ((size_t)(b * HKn + hk) * Dh + d) * T_LEN + tloc;
#pragma unroll
    for (int p = 0; p < 2; ++p)
      *(uint4*)(dst + p * 8) = *(uint4*)&tmp[p * 8];
  }
}

// ---------------------------------------------------------------------------
// Output projection GEMM. R20 = R18 exact: BM=BN=64, counted-vmcnt skeleton,
// 32 KB LDS -> 5 blk/CU. grid (64,16) = 1024 blocks.
// ---------------------------------------------------------------------------
__global__ __launch_bounds__(256) void gemm_wo(
    const u16* __restrict__ A, const u16* __restrict__ B,
    float* __restrict__ C, int N, int K)
{
  const int NT = K / 64;
  __shared__ u16 smem[16384];           // As[2][4096] + Bs[2][4096]
  u16* As = smem;
  u16* Bs = smem + 8192;
  const int tid = threadIdx.x;
  const int wave = tid >> 6, lane = tid & 63;
  const int quad = lane >> 4, lanelow = lane & 15;
  const int row0 = blockIdx.x * 64;
  const int col0 = blockIdx.y * 64;
  const int wm = (wave >> 1) * 32, wn = (wave & 1) * 32;

  f32x4 acc[2][2];
#pragma unroll
  for (int i = 0; i < 2; ++i)
#pragma unroll
    for (int j = 0; j < 2; ++j) acc[i][j] = (f32x4){0.f, 0.f, 0.f, 0.f};

  auto stage = [&](int buf, int k0) {
#pragma unroll
    for (int s = 0; s < 2; ++s) {
      int slot = s * 256 + tid;
      int r = slot >> 3, g = (slot & 7) ^ (r & 7);
      async_copy16(A + (size_t)(row0 + r) * K + k0 + g * 8,
                   &As[buf * 4096 + slot * 8]);
    }
#pragma unroll
    for (int s = 0; s < 2; ++s) {
      int slot = s * 256 + tid;
      int r = slot >> 3, g = (slot & 7) ^ (r & 7);
      async_copy16(B + (size_t)(col0 + r) * K + k0 + g * 8,
                   &Bs[buf * 4096 + slot * 8]);
    }
  };

  stage(0, 0);
  stage(1, 64);
  int cur = 0;
  for (int t = 0; t < NT; ++t) {
    if (t < NT - 1) asm volatile("s_waitcnt vmcnt(4)" ::: "memory");
    else            asm volatile("s_waitcnt vmcnt(0)" ::: "memory");
    __builtin_amdgcn_s_barrier();
    __builtin_amdgcn_sched_barrier(0);
#pragma unroll
    for (int kk = 0; kk < 2; ++kk) {
      bf16x8 a[2], b[2];
#pragma unroll
      for (int i = 0; i < 2; ++i) {
        int r = wm + i * 16 + lanelow;
        a[i] = *(const bf16x8*)&As[cur * 4096 + r * 64 + (((kk * 4 + quad) ^ (r & 7)) * 8)];
      }
#pragma unroll
      for (int j = 0; j < 2; ++j) {
        int r = wn + j * 16 + lanelow;
        b[j] = *(const bf16x8*)&Bs[cur * 4096 + r * 64 + (((kk * 4 + quad) ^ (r & 7)) * 8)];
      }
      __builtin_amdgcn_s_setprio(1);
#pragma unroll
      for (int i = 0; i < 2; ++i)
#pragma unroll
        for (int j = 0; j < 2; ++j)
          acc[i][j] = __builtin_amdgcn_mfma_f32_16x16x32_bf16(a[i], b[j], acc[i][j], 0, 0, 0);
      __builtin_amdgcn_s_setprio(0);
    }
    __builtin_amdgcn_sched_barrier(0);
    __builtin_amdgcn_s_barrier();
    if (t + 2 < NT) stage(cur, (t + 2) * 64);
    cur ^= 1;
  }

#pragma unroll
  for (int i = 0; i < 2; ++i)
#pragma unroll
    for (int j = 0; j < 2; ++j) {
      int r = row0 + wm + i * 16 + quad * 4;
      int c = col0 + wn + j * 16 + lanelow;
#pragma unroll
      for (int reg = 0; reg < 4; ++reg)
        C[(size_t)(r + reg) * N + c] = acc[i][j][reg];
    }
}

// ---------------------------------------------------------------------------
// MFMA flash attention. R20: TWO q-heads per block (GQA reuse). Heads
// (2y, 2y+1) share hk = y>>1, so one K/V staging pipeline feeds BOTH:
// K/V global traffic, barriers, and LDS aK/aV reads per MFMA all halve.
// T14 async-STAGE split kept (R18 win). grid (32, 8, 2) = 512 blocks.
// ---------------------------------------------------------------------------
__global__ __launch_bounds__(256) void attn_mfma(
    const u16* __restrict__ qa, const u16* __restrict__ ka,
    const u16* __restrict__ vt_g, u16* __restrict__ att)
{
  __shared__ u16 Ks[2][64 * PS];    // [buf][j][d]
  __shared__ u16 Vt[2][64 * PSV];   // [buf][d][j]
  const int bx = blockIdx.x, hp = blockIdx.y, b = blockIdx.z;
  // --- load-balance permutation: bijective in bx for each (hp,b) ---
  const int j5 = bx & 7;
  const int t5 = (bx >> 3) & 3;
  const int tu = (t5 + (hp >> 2) + 2 * b) & 3;
  const int qt = (tu == 0) ? j5
               : (tu == 1) ? (15 - j5)
                           : (16 + 2 * j5 + (tu & 1));
  const int h0 = hp * 2;            // q-heads h0, h0+1 (same KV group)
  const int hk = h0 >> 2;
  const int qb = qt * 64;
  const int tid = threadIdx.x;
  const int wave = tid >> 6, lane = tid & 63;
  const int quad = lane >> 4, lanelow = lane & 15;

  bf16x8 aQ[2][2];                  // [sub-head][k-half]
#pragma unroll
  for (int s = 0; s < 2; ++s)
#pragma unroll
    for (int kk = 0; kk < 2; ++kk)
      aQ[s][kk] = *(const bf16x8*)(qa +
          ((size_t)(b * T_LEN + qb + wave * 16 + lanelow) * HQn + h0 + s) * Dh +
          kk * 32 + quad * 8);

  f32x4 O[2][4];
  float l[2] = {0.f, 0.f};
#pragma unroll
  for (int s = 0; s < 2; ++s)
#pragma unroll
    for (int dt = 0; dt < 4; ++dt) O[s][dt] = (f32x4){0.f, 0.f, 0.f, 0.f};

  const int kt0 = (qt >= 16) ? qt - 16 : 0;
  const int kt1 = qt;

  const int sr0 = tid >> 3,         sc0 = (tid & 7) * 8;
  const int sr1 = (tid + 256) >> 3, sc1 = ((tid + 256) & 7) * 8;
  const u16* kg = ka + (size_t)(b * T_LEN) * (HKn * Dh) + hk * Dh;
  const u16* vg = vt_g + (size_t)(b * HKn + hk) * Dh * T_LEN;

  {
    const int kb = kt0 * 64;
    uint4 k0 = *(const uint4*)(kg + (size_t)(kb + sr0) * (HKn * Dh) + sc0);
    uint4 k1 = *(const uint4*)(kg + (size_t)(kb + sr1) * (HKn * Dh) + sc1);
    uint4 v0 = *(const uint4*)(vg + (size_t)sr0 * T_LEN + kb + sc0);
    uint4 v1 = *(const uint4*)(vg + (size_t)sr1 * T_LEN + kb + sc1);
    *(uint4*)&Ks[0][sr0 * PS + sc0] = k0;
    *(uint4*)&Ks[0][sr1 * PS + sc1] = k1;
    *(uint2*)&Vt[0][sr0 * PSV + sc0]     = make_uint2(v0.x, v0.y);
    *(uint2*)&Vt[0][sr0 * PSV + sc0 + 4] = make_uint2(v0.z, v0.w);
    *(uint2*)&Vt[0][sr1 * PSV + sc1]     = make_uint2(v1.x, v1.y);
    *(uint2*)&Vt[0][sr1 * PSV + sc1 + 4] = make_uint2(v1.z, v1.w);
  }

  for (int kt = kt0; kt <= kt1; ++kt) {
    const int buf = (kt - kt0) & 1;
    const int kb = kt * 64;
    uint4 k0, k1, v0, v1;
    const bool more = (kt < kt1);
    if (more) {
      const int nb = kb + 64;
      k0 = *(const uint4*)(kg + (size_t)(nb + sr0) * (HKn * Dh) + sc0);
      k1 = *(const uint4*)(kg + (size_t)(nb + sr1) * (HKn * Dh) + sc1);
      v0 = *(const uint4*)(vg + (size_t)sr0 * T_LEN + nb + sc0);
      v1 = *(const uint4*)(vg + (size_t)sr1 * T_LEN + nb + sc1);
    }
    // T14: LDS-only fence + raw barrier; global loads stay in flight.
    __builtin_amdgcn_sched_barrier(0);
    asm volatile("s_waitcnt lgkmcnt(0)" ::: "memory");
    __builtin_amdgcn_s_barrier();
    __builtin_amdgcn_sched_barrier(0);

    f32x4 St[2][4];
#pragma unroll
    for (int jt = 0; jt < 4; ++jt) {
      bf16x8 aK0 = *(const bf16x8*)&Ks[buf][(jt * 16 + lanelow) * PS + quad * 8];
      bf16x8 aK1 = *(const bf16x8*)&Ks[buf][(jt * 16 + lanelow) * PS + 32 + quad * 8];
#pragma unroll
      for (int s = 0; s < 2; ++s) {
        f32x4 acc = (f32x4){-12.f, -12.f, -12.f, -12.f};
        acc = __builtin_amdgcn_mfma_f32_16x16x32_bf16(aK0, aQ[s][0], acc, 0, 0, 0);
        acc = __builtin_amdgcn_mfma_f32_16x16x32_bf16(aK1, aQ[s][1], acc, 0, 0, 0);
        St[s][jt] = acc;
      }
    }
    if (kt == kt1) {
#pragma unroll
      for (int jt = 0; jt < 4; ++jt)
#pragma unroll
        for (int rr = 0; rr < 4; ++rr) {
          int ig = qb + wave * 16 + lanelow;
          int jg = kb + jt * 16 + quad * 4 + rr;
          if (jg > ig) { St[0][jt][rr] = -1e30f; St[1][jt][rr] = -1e30f; }
        }
    } else if (kt == kt0 && qt >= 16) {
#pragma unroll
      for (int jt = 0; jt < 4; ++jt)
#pragma unroll
        for (int rr = 0; rr < 4; ++rr) {
          int ig = qb + wave * 16 + lanelow;
          int jg = kb + jt * 16 + quad * 4 + rr;
          if (jg < ig - WIN) { St[0][jt][rr] = -1e30f; St[1][jt][rr] = -1e30f; }
        }
    }
    bf16x4 Pt[2][4];
#pragma unroll
    for (int s = 0; s < 2; ++s)
#pragma unroll
      for (int jt = 0; jt < 4; ++jt) {
        float p0 = __builtin_amdgcn_exp2f(St[s][jt][0]);
        float p1 = __builtin_amdgcn_exp2f(St[s][jt][1]);
        float p2 = __builtin_amdgcn_exp2f(St[s][jt][2]);
        float p3 = __builtin_amdgcn_exp2f(St[s][jt][3]);
        l[s] += (p0 + p1) + (p2 + p3);
        union { uint2 u; bf16x4 v; } pu;
        pu.u.x = pack_bf2(p1, p0);
        pu.u.y = pack_bf2(p3, p2);
        Pt[s][jt] = pu.v;
      }
#pragma unroll
    for (int dt = 0; dt < 4; ++dt)
#pragma unroll
      for (int jt = 0; jt < 4; ++jt) {
        bf16x4 aV = *(const bf16x4*)&Vt[buf][(dt * 16 + lanelow) * PSV + jt * 16 + quad * 4];
        O[0][dt] = MFMA16(aV, Pt[0][jt], O[0][dt]);
        O[1][dt] = MFMA16(aV, Pt[1][jt], O[1][dt]);
      }
    if (more) {
      // T14: drain THIS wave's 4 loads only now, after compute hid latency.
      __builtin_amdgcn_sched_barrier(0);
      asm volatile("s_waitcnt vmcnt(0)" ::: "memory");
      __builtin_amdgcn_sched_barrier(0);
      const int nbuf = buf ^ 1;
      *(uint4*)&Ks[nbuf][sr0 * PS + sc0] = k0;
      *(uint4*)&Ks[nbuf][sr1 * PS + sc1] = k1;
      *(uint2*)&Vt[nbuf][sr0 * PSV + sc0]     = make_uint2(v0.x, v0.y);
      *(uint2*)&Vt[nbuf][sr0 * PSV + sc0 + 4] = make_uint2(v0.z, v0.w);
      *(uint2*)&Vt[nbuf][sr1 * PSV + sc1]     = make_uint2(v1.x, v1.y);
      *(uint2*)&Vt[nbuf][sr1 * PSV + sc1 + 4] = make_uint2(v1.z, v1.w);
    }
  }

#pragma unroll
  for (int s = 0; s < 2; ++s) {
    float sum = l[s];
    sum += __shfl_xor(sum, 16, 64);
    sum += __shfl_xor(sum, 32, 64);
    float inv = 1.f / sum;
    int qg = qb + wave * 16 + lanelow;
    u16* obase = att + (size_t)(b * T_LEN + qg) * E_DIM + (h0 + s) * Dh;
#pragma unroll
    for (int dt = 0; dt < 4; ++dt) {
      bf16x4 ov;
      ov[0] = (short)f2bf(O[s][dt][0] * inv);
      ov[1] = (short)f2bf(O[s][dt][1] * inv);
      ov[2] = (short)f2bf(O[s][dt][2] * inv);
      ov[3] = (short)f2bf(O[s][dt][3] * inv);
      *(bf16x4*)(obase + dt * 16 + quad * 4) = ov;
    }
  }
}

// ---------------------------------------------------------------------------
extern "C" void kernel_launch(void* const* d_in, const int* in_sizes, int n_in,
                              void* d_out, int out_size, void* d_ws, size_t ws_size,
                              hipStream_t stream)
{
  const float* x    = (const float*)d_in[0];
  const float* ve   = (const float*)d_in[1];
  const float* rc   = (const float*)d_in[2];
  const float* rs   = (const float*)d_in[3];
  const float* wqkv = (const float*)d_in[4];
  const float* wg   = (const float*)d_in[5];
  const float* wo   = (const float*)d_in[6];
  float* out = (float*)d_out;

  char* ws = (char*)d_ws;
  // ws layout — ALL ranges disjoint:
  //   [0,        8388608)  x_bf      4096x1024 bf16
  //   [8388608, 11534336)  wqkv_bf   1536x1024 bf16
  //   [11534336,13631488)  wo_bf     1024x1024 bf16
  //   [13631488,22020096)  q_att     4096x16x64 bf16
  //   [22020096,24117248)  k_att     4096x4x64 bf16
  //   [24117248,26214400)  v_t       (2*4*64)x2048 bf16
  //   [26214400,34603008)  att       4096x1024 bf16
  u16* x_bf    = (u16*)(ws);
  u16* wqkv_bf = (u16*)(ws + 8388608);
  u16* wo_bf   = (u16*)(ws + 11534336);
  u16* q_att   = (u16*)(ws + 13631488);
  u16* k_att   = (u16*)(ws + 22020096);
  u16* v_t     = (u16*)(ws + 24117248);
  u16* att     = (u16*)(ws + 26214400);

  cvt_all<<<6656, 256, 0, stream>>>((const float4*)x, (const float4*)wqkv,
                                    (const float4*)wo, (uint2*)x_bf,
                                    (uint2*)wqkv_bf, (uint2*)wo_bf);
  gemm_qkv<<<dim3(64, 24), 256, 0, stream>>>(x_bf, wqkv_bf, x, ve, rc, rs, wg,
                                             q_att, k_att, v_t);
  attn_mfma<<<dim3(T_LEN / 64, HQn / 2, NB), 256, 0, stream>>>(q_att, k_att, v_t, att);
  gemm_wo<<<dim3(64, 16), 256, 0, stream>>>(att, wo_bf, out, E_DIM, E_DIM);
}